// Round 1
// baseline (497.889 us; speedup 1.0000x reference)
//
#include <hip/hip_runtime.h>

#define Bb 64
#define Tt 256
#define Hh 512
#define Ww 1024
#define HW (Hh * Ww)
#define EPSF 1e-5f

// ---------------------------------------------------------------------------
// Kernel 1: compute interp points, write them to out, scatter 1.0 into the
// (pre-zeroed) visitation map, count distinct visited cells per batch.
// ---------------------------------------------------------------------------
__global__ void scatter_kernel(const float* __restrict__ gt,
                               float* __restrict__ out_pts,
                               float* __restrict__ vis,
                               int* __restrict__ count,
                               int ms, int P) {
    int tid = blockIdx.x * blockDim.x + threadIdx.x;
    int total = Bb * P;
    if (tid >= total) return;
    int b = tid / P;
    int idx = tid - b * P;

    float px, py;
    int segN = (Tt - 1) * ms;
    if (idx < segN) {
        int seg = idx / ms;
        int k = idx - seg * ms;
        const float* g0 = gt + (size_t)(b * Tt + seg) * 9;
        // xy = gt[:, :, :2, 2] / 2.0  (exact)
        float sx = g0[2] * 0.5f, sy = g0[5] * 0.5f;
        float ex = g0[11] * 0.5f, ey = g0[14] * 0.5f;  // next row: +9 offset
        float t = (ms > 1) ? (float)k / (float)(ms - 1) : 0.0f;
        // match reference: start + t*(end-start), no FMA contraction
        px = __fadd_rn(sx, __fmul_rn(t, __fsub_rn(ex, sx)));
        py = __fadd_rn(sy, __fmul_rn(t, __fsub_rn(ey, sy)));
    } else {
        const float* g0 = gt + (size_t)(b * Tt + (Tt - 1)) * 9;
        px = g0[2] * 0.5f;
        py = g0[5] * 0.5f;
    }
    out_pts[(size_t)tid * 2]     = px;
    out_pts[(size_t)tid * 2 + 1] = py;

    int xi = (int)fminf(fmaxf(px, 0.0f), (float)(Hh - 1));
    int yi = (int)fminf(fmaxf(py, 0.0f), (float)(Ww - 1));
    size_t lin = (size_t)b * HW + (size_t)(xi * Ww + yi);
    float old = atomicExch(&vis[lin], 1.0f);
    if (old == 0.0f) atomicAdd(&count[b], 1);
}

// ---------------------------------------------------------------------------
// Kernel 2: fused normalize + per-batch reductions.
// 256 blocks per batch, each block owns a contiguous 2048-element chunk.
// ---------------------------------------------------------------------------
#define CHUNK 2048
#define BLOCKS_PER_B (HW / CHUNK)  // 256

__global__ __launch_bounds__(256) void reduce_norm_kernel(
        const float* __restrict__ exps, const float* __restrict__ rew,
        float* __restrict__ vis, const int* __restrict__ count,
        double* __restrict__ esum, double* __restrict__ edot,
        double* __restrict__ vdot) {
    int b = blockIdx.x / BLOCKS_PER_B;
    int c = blockIdx.x % BLOCKS_PER_B;
    size_t base = (size_t)b * HW + (size_t)c * CHUNK;
    float recip = 1.0f / ((float)count[b] + EPSF);

    float es = 0.0f, ed = 0.0f, vd = 0.0f;
    for (int i = threadIdx.x; i < CHUNK; i += 256) {
        size_t j = base + i;
        float v = vis[j];
        float e = exps[j];
        float r = rew[j];
        es += e;
        ed += e * r;
        vd += v * r;
        vis[j] = v * recip;  // v in {0,1} -> exact match to ref division
    }

    // wave (64-lane) tree reduce, then cross-wave via LDS
    for (int off = 32; off; off >>= 1) {
        es += __shfl_down(es, off);
        ed += __shfl_down(ed, off);
        vd += __shfl_down(vd, off);
    }
    __shared__ float s_es[4], s_ed[4], s_vd[4];
    int lane = threadIdx.x & 63;
    int wv = threadIdx.x >> 6;
    if (lane == 0) { s_es[wv] = es; s_ed[wv] = ed; s_vd[wv] = vd; }
    __syncthreads();
    if (threadIdx.x == 0) {
        float tes = 0.0f, ted = 0.0f, tvd = 0.0f;
        for (int w = 0; w < 4; ++w) { tes += s_es[w]; ted += s_ed[w]; tvd += s_vd[w]; }
        atomicAdd(&esum[b], (double)tes);
        atomicAdd(&edot[b], (double)ted);
        atomicAdd(&vdot[b], (double)tvd);
    }
}

// ---------------------------------------------------------------------------
// Kernel 3: final loss = mean_b(edot/(esum+eps)) - mean_b(vdot/(count+eps))
// ---------------------------------------------------------------------------
__global__ void loss_kernel(const double* __restrict__ esum,
                            const double* __restrict__ edot,
                            const double* __restrict__ vdot,
                            const int* __restrict__ count,
                            float* __restrict__ loss_out) {
    int b = threadIdx.x;  // 64 threads = 1 wave
    double e = edot[b] / (esum[b] + 1e-5);
    double v = vdot[b] / ((double)count[b] + 1e-5);
    double term = e - v;
    for (int off = 32; off; off >>= 1) term += __shfl_down(term, off);
    if (b == 0) loss_out[0] = (float)(term / (double)Bb);
}

extern "C" void kernel_launch(void* const* d_in, const int* in_sizes, int n_in,
                              void* d_out, int out_size, void* d_ws, size_t ws_size,
                              hipStream_t stream) {
    const float* gt   = (const float*)d_in[0];
    const float* exps = (const float*)d_in[1];
    const float* rew  = (const float*)d_in[2];
    float* out = (float*)d_out;

    // out layout: [loss(1)] [svf (B*H*W)] [interp_pts (B*P*2)]
    float* loss_out = out;
    float* svf = out + 1;
    int P  = (out_size - 1 - Bb * HW) / (Bb * 2);
    int ms = (P - 1) / (Tt - 1);
    float* pts = out + 1 + (size_t)Bb * HW;

    // ws layout: int count[64] (256B), then 3x double[64]
    int* count   = (int*)d_ws;
    double* esum = (double*)((char*)d_ws + 256);
    double* edot = esum + Bb;
    double* vdot = edot + Bb;

    hipMemsetAsync(svf, 0, (size_t)Bb * HW * sizeof(float), stream);
    hipMemsetAsync(d_ws, 0, 256 + 3 * Bb * sizeof(double), stream);

    int total = Bb * P;
    scatter_kernel<<<(total + 255) / 256, 256, 0, stream>>>(gt, pts, svf, count, ms, P);
    reduce_norm_kernel<<<Bb * BLOCKS_PER_B, 256, 0, stream>>>(exps, rew, svf, count,
                                                              esum, edot, vdot);
    loss_kernel<<<1, 64, 0, stream>>>(esum, edot, vdot, count, loss_out);
}

// Round 2
// 452.869 us; speedup vs baseline: 1.0994x; 1.0994x over previous
//
#include <hip/hip_runtime.h>

#define Bb 64
#define Tt 256
#define Hh 512
#define Ww 1024
#define HW (Hh * Ww)          // 524288
#define EPSF 1e-5f

// ws layout:
//   [0,256)      int   count[64]
//   [256,768)    double esum[64]
//   [768,1280)   double edot[64]
//   [1280,1792)  double vdot[64]
//   [4096, 4096+4MB)  uint32 visited-bitmask, HW/32=16384 words per batch
#define WS_MASK_OFF 4096
#define MASK_WORDS_PER_B (HW / 32)   // 16384

// ---------------------------------------------------------------------------
// Kernel A: float4 read exp_svf & reward, reduce per-batch esum/edot,
// write svf zeros (svf = out+1 is 4B-offset; use shifted float4 + edges).
// Block owns 8192 contiguous floats of one batch. Grid = 64*64 = 4096.
// ---------------------------------------------------------------------------
__global__ __launch_bounds__(256) void fused_reduce_zero(
        const float* __restrict__ exps, const float* __restrict__ rew,
        float* __restrict__ svf,
        double* __restrict__ esum, double* __restrict__ edot) {
    int b = blockIdx.x >> 6;          // / 64 blocks-per-batch
    int c = blockIdx.x & 63;
    size_t base = (size_t)b * HW + (size_t)c * 8192;

    const float4* e4 = (const float4*)(exps + base);
    const float4* r4 = (const float4*)(rew + base);

    float es = 0.0f, ed = 0.0f;
    #pragma unroll
    for (int k = 0; k < 8; ++k) {
        int i = threadIdx.x + k * 256;      // 0..2047
        float4 e = e4[i];
        float4 r = r4[i];
        es += (e.x + e.y) + (e.z + e.w);
        ed += (e.x * r.x + e.y * r.y) + (e.z * r.z + e.w * r.w);
    }

    // zero-fill svf[base .. base+8192): svf+base+3 is 16B-aligned
    {
        float4* z4 = (float4*)(svf + base + 3);   // covers base+3 .. base+8190
        float4 z = make_float4(0.f, 0.f, 0.f, 0.f);
        #pragma unroll
        for (int k = 0; k < 8; ++k) {
            int i = threadIdx.x + k * 256;
            if (i < 2047) z4[i] = z;
        }
        if (threadIdx.x < 3) svf[base + threadIdx.x] = 0.0f;   // head
        if (threadIdx.x == 3) svf[base + 8191] = 0.0f;         // tail
    }

    // wave tree reduce + cross-wave LDS
    for (int off = 32; off; off >>= 1) {
        es += __shfl_down(es, off);
        ed += __shfl_down(ed, off);
    }
    __shared__ float s_es[4], s_ed[4];
    int lane = threadIdx.x & 63, wv = threadIdx.x >> 6;
    if (lane == 0) { s_es[wv] = es; s_ed[wv] = ed; }
    __syncthreads();
    if (threadIdx.x == 0) {
        float tes = (s_es[0] + s_es[1]) + (s_es[2] + s_es[3]);
        float ted = (s_ed[0] + s_ed[1]) + (s_ed[2] + s_ed[3]);
        atomicAdd(&esum[b], (double)tes);
        atomicAdd(&edot[b], (double)ted);
    }
}

// ---------------------------------------------------------------------------
// Kernel B: interp points -> out, claim cells in bitmask; first claim bumps
// count[b] and accumulates vdot[b] += reward[cell].
// ---------------------------------------------------------------------------
__global__ void scatter_kernel(const float* __restrict__ gt,
                               const float* __restrict__ rew,
                               float* __restrict__ out_pts,
                               unsigned int* __restrict__ mask,
                               int* __restrict__ count,
                               double* __restrict__ vdot,
                               int ms, int P) {
    int tid = blockIdx.x * blockDim.x + threadIdx.x;
    if (tid >= Bb * P) return;
    int b = tid / P;
    int idx = tid - b * P;

    float px, py;
    int segN = (Tt - 1) * ms;
    if (idx < segN) {
        int seg = idx / ms;
        int k = idx - seg * ms;
        const float* g0 = gt + (size_t)(b * Tt + seg) * 9;
        float sx = g0[2] * 0.5f, sy = g0[5] * 0.5f;
        float ex = g0[11] * 0.5f, ey = g0[14] * 0.5f;
        float t = (ms > 1) ? (float)k / (float)(ms - 1) : 0.0f;
        px = __fadd_rn(sx, __fmul_rn(t, __fsub_rn(ex, sx)));
        py = __fadd_rn(sy, __fmul_rn(t, __fsub_rn(ey, sy)));
    } else {
        const float* g0 = gt + (size_t)(b * Tt + (Tt - 1)) * 9;
        px = g0[2] * 0.5f;
        py = g0[5] * 0.5f;
    }
    out_pts[(size_t)tid * 2]     = px;
    out_pts[(size_t)tid * 2 + 1] = py;

    int xi = (int)fminf(fmaxf(px, 0.0f), (float)(Hh - 1));
    int yi = (int)fminf(fmaxf(py, 0.0f), (float)(Ww - 1));
    int cell = xi * Ww + yi;

    unsigned int bit = 1u << (cell & 31);
    unsigned int old = atomicOr(&mask[b * MASK_WORDS_PER_B + (cell >> 5)], bit);
    if (!(old & bit)) {
        atomicAdd(&count[b], 1);
        atomicAdd(&vdot[b], (double)rew[(size_t)b * HW + cell]);
    }
}

// ---------------------------------------------------------------------------
// Kernel C: write recip at visited cells (duplicates write identical value).
// ---------------------------------------------------------------------------
__global__ void fixup_kernel(const float* __restrict__ pts,
                             const int* __restrict__ count,
                             float* __restrict__ svf, int P) {
    int tid = blockIdx.x * blockDim.x + threadIdx.x;
    if (tid >= Bb * P) return;
    int b = tid / P;
    float px = pts[(size_t)tid * 2];
    float py = pts[(size_t)tid * 2 + 1];
    int xi = (int)fminf(fmaxf(px, 0.0f), (float)(Hh - 1));
    int yi = (int)fminf(fmaxf(py, 0.0f), (float)(Ww - 1));
    float recip = 1.0f / ((float)count[b] + EPSF);
    svf[(size_t)b * HW + xi * Ww + yi] = recip;
}

// ---------------------------------------------------------------------------
// Kernel D: loss
// ---------------------------------------------------------------------------
__global__ void loss_kernel(const double* __restrict__ esum,
                            const double* __restrict__ edot,
                            const double* __restrict__ vdot,
                            const int* __restrict__ count,
                            float* __restrict__ loss_out) {
    int b = threadIdx.x;  // 64 threads = 1 wave
    double e = edot[b] / (esum[b] + 1e-5);
    double v = vdot[b] / ((double)count[b] + 1e-5);
    double term = e - v;
    for (int off = 32; off; off >>= 1) term += __shfl_down(term, off);
    if (b == 0) loss_out[0] = (float)(term / (double)Bb);
}

extern "C" void kernel_launch(void* const* d_in, const int* in_sizes, int n_in,
                              void* d_out, int out_size, void* d_ws, size_t ws_size,
                              hipStream_t stream) {
    const float* gt   = (const float*)d_in[0];
    const float* exps = (const float*)d_in[1];
    const float* rew  = (const float*)d_in[2];
    float* out = (float*)d_out;

    float* loss_out = out;
    float* svf = out + 1;
    int P  = (out_size - 1 - Bb * HW) / (Bb * 2);
    int ms = (P - 1) / (Tt - 1);
    float* pts = out + 1 + (size_t)Bb * HW;

    int* count   = (int*)d_ws;
    double* esum = (double*)((char*)d_ws + 256);
    double* edot = (double*)((char*)d_ws + 768);
    double* vdot = (double*)((char*)d_ws + 1280);
    unsigned int* mask = (unsigned int*)((char*)d_ws + WS_MASK_OFF);

    // zero count/accumulators + bitmask (4MB + header)
    hipMemsetAsync(d_ws, 0, WS_MASK_OFF + (size_t)Bb * MASK_WORDS_PER_B * 4, stream);

    fused_reduce_zero<<<Bb * 64, 256, 0, stream>>>(exps, rew, svf, esum, edot);
    int total = Bb * P;
    scatter_kernel<<<(total + 255) / 256, 256, 0, stream>>>(gt, rew, pts, mask,
                                                            count, vdot, ms, P);
    fixup_kernel<<<(total + 255) / 256, 256, 0, stream>>>(pts, count, svf, P);
    loss_kernel<<<1, 64, 0, stream>>>(esum, edot, vdot, count, loss_out);
}

// Round 4
// 346.742 us; speedup vs baseline: 1.4359x; 1.3061x over previous
//
#include <hip/hip_runtime.h>

#define Bb 64
#define Tt 256
#define Hh 512
#define Ww 1024
#define HW (Hh * Ww)          // 524288
#define EPSF 1e-5f

typedef float vf4 __attribute__((ext_vector_type(4)));

// ws layout:
//   [0,256)        int    count[64]
//   [256,768)      double vdot[64]
//   [768,33536)    double esum_p[4096]   (64 blocks per batch)
//   [33536,66304)  double edot_p[4096]
// Everything is written before it is read -> no memset needed.

// ---------------------------------------------------------------------------
// Kernel A: float4 read exp_svf & reward, per-block partial esum/edot to
// distinct ws slots (no atomics), nontemporal zero-fill of svf.
// Block owns 8192 contiguous floats of one batch. Grid = 64*64 = 4096.
// ---------------------------------------------------------------------------
__global__ __launch_bounds__(256) void fused_reduce_zero(
        const float* __restrict__ exps, const float* __restrict__ rew,
        float* __restrict__ svf,
        double* __restrict__ esum_p, double* __restrict__ edot_p) {
    int b = blockIdx.x >> 6;
    int c = blockIdx.x & 63;
    size_t base = (size_t)b * HW + (size_t)c * 8192;

    const float4* e4 = (const float4*)(exps + base);
    const float4* r4 = (const float4*)(rew + base);

    float es = 0.0f, ed = 0.0f;
    #pragma unroll
    for (int k = 0; k < 8; ++k) {
        int i = threadIdx.x + k * 256;      // 0..2047
        float4 e = e4[i];
        float4 r = r4[i];
        es += (e.x + e.y) + (e.z + e.w);
        ed += (e.x * r.x + e.y * r.y) + (e.z * r.z + e.w * r.w);
    }

    // zero-fill svf[base .. base+8192): svf = out+1, so svf+base+3 is 16B-aligned
    {
        vf4* z4 = (vf4*)(svf + base + 3);
        vf4 z = {0.f, 0.f, 0.f, 0.f};
        #pragma unroll
        for (int k = 0; k < 8; ++k) {
            int i = threadIdx.x + k * 256;
            if (i < 2047) __builtin_nontemporal_store(z, &z4[i]);
        }
        if (threadIdx.x < 3) svf[base + threadIdx.x] = 0.0f;
        if (threadIdx.x == 3) svf[base + 8191] = 0.0f;
    }

    for (int off = 32; off; off >>= 1) {
        es += __shfl_down(es, off);
        ed += __shfl_down(ed, off);
    }
    __shared__ float s_es[4], s_ed[4];
    int lane = threadIdx.x & 63, wv = threadIdx.x >> 6;
    if (lane == 0) { s_es[wv] = es; s_ed[wv] = ed; }
    __syncthreads();
    if (threadIdx.x == 0) {
        float tes = (s_es[0] + s_es[1]) + (s_es[2] + s_es[3]);
        float ted = (s_ed[0] + s_ed[1]) + (s_ed[2] + s_ed[3]);
        esum_p[blockIdx.x] = (double)tes;
        edot_p[blockIdx.x] = (double)ted;
    }
}

// ---------------------------------------------------------------------------
// Point computation (bit-identical to what the reference produces at fp32)
// ---------------------------------------------------------------------------
__device__ __forceinline__ void comp_pt(const float* __restrict__ gt, int b,
                                        int idx, int ms, int segN,
                                        float& px, float& py) {
    if (idx < segN) {
        int seg = idx / ms;
        int k = idx - seg * ms;
        const float* g0 = gt + (size_t)(b * Tt + seg) * 9;
        float sx = g0[2] * 0.5f, sy = g0[5] * 0.5f;
        float ex = g0[11] * 0.5f, ey = g0[14] * 0.5f;
        float t = (ms > 1) ? (float)k / (float)(ms - 1) : 0.0f;
        px = __fadd_rn(sx, __fmul_rn(t, __fsub_rn(ex, sx)));
        py = __fadd_rn(sy, __fmul_rn(t, __fsub_rn(ey, sy)));
    } else {
        const float* g0 = gt + (size_t)(b * Tt + (Tt - 1)) * 9;
        px = g0[2] * 0.5f;
        py = g0[5] * 0.5f;
    }
}

__device__ __forceinline__ int pt_cell(float px, float py) {
    int xi = (int)fminf(fmaxf(px, 0.0f), (float)(Hh - 1));
    int yi = (int)fminf(fmaxf(py, 0.0f), (float)(Ww - 1));
    return xi * Ww + yi;
}

// ---------------------------------------------------------------------------
// Kernel B: one block per batch. Cells are MONOTONE along the point sequence
// (steps >= 0 -> both coords non-decreasing -> x*W+y non-decreasing), so
// dedup == adjacent-compare. No atomics anywhere.
// ---------------------------------------------------------------------------
__global__ __launch_bounds__(256) void scatter_batch(
        const float* __restrict__ gt, const float* __restrict__ rew,
        float* __restrict__ pts, float* __restrict__ svf,
        int* __restrict__ count_out, double* __restrict__ vdot_out,
        int ms, int P) {
    int b = blockIdx.x;
    int segN = (Tt - 1) * ms;

    int myCount = 0;
    float myV = 0.0f;
    for (int idx = threadIdx.x; idx < P; idx += 256) {
        float px, py;
        comp_pt(gt, b, idx, ms, segN, px, py);
        size_t pi = ((size_t)b * P + idx) * 2;
        pts[pi]     = px;
        pts[pi + 1] = py;
        int cell = pt_cell(px, py);
        bool claim;
        if (idx == 0) {
            claim = true;
        } else {
            float qx, qy;
            comp_pt(gt, b, idx - 1, ms, segN, qx, qy);
            claim = (pt_cell(qx, qy) != cell);
        }
        if (claim) {
            myCount++;
            myV += rew[(size_t)b * HW + cell];
        }
    }

    for (int off = 32; off; off >>= 1) {
        myCount += __shfl_down(myCount, off);
        myV     += __shfl_down(myV, off);
    }
    __shared__ int   sc[4];
    __shared__ float sv[4];
    __shared__ float s_recip;
    int lane = threadIdx.x & 63, wv = threadIdx.x >> 6;
    if (lane == 0) { sc[wv] = myCount; sv[wv] = myV; }
    __syncthreads();
    if (threadIdx.x == 0) {
        int tot  = (sc[0] + sc[1]) + (sc[2] + sc[3]);
        float tv = (sv[0] + sv[1]) + (sv[2] + sv[3]);
        count_out[b] = tot;
        vdot_out[b]  = (double)tv;
        s_recip = 1.0f / ((float)tot + EPSF);
    }
    __syncthreads();
    float recip = s_recip;

    // write recip at visited cells (duplicates write the identical value)
    for (int idx = threadIdx.x; idx < P; idx += 256) {
        size_t pi = ((size_t)b * P + idx) * 2;
        float px = pts[pi], py = pts[pi + 1];
        svf[(size_t)b * HW + pt_cell(px, py)] = recip;
    }
}

// ---------------------------------------------------------------------------
// Kernel C: loss
// ---------------------------------------------------------------------------
__global__ void loss_kernel(const double* __restrict__ esum_p,
                            const double* __restrict__ edot_p,
                            const double* __restrict__ vdot,
                            const int* __restrict__ count,
                            float* __restrict__ loss_out) {
    int b = threadIdx.x;  // 64 threads = 1 wave
    double es = 0.0, ed = 0.0;
    #pragma unroll 8
    for (int c = 0; c < 64; ++c) {
        es += esum_p[b * 64 + c];
        ed += edot_p[b * 64 + c];
    }
    double e = ed / (es + 1e-5);
    double v = vdot[b] / ((double)count[b] + 1e-5);
    double term = e - v;
    for (int off = 32; off; off >>= 1) term += __shfl_down(term, off);
    if (b == 0) loss_out[0] = (float)(term / (double)Bb);
}

extern "C" void kernel_launch(void* const* d_in, const int* in_sizes, int n_in,
                              void* d_out, int out_size, void* d_ws, size_t ws_size,
                              hipStream_t stream) {
    const float* gt   = (const float*)d_in[0];
    const float* exps = (const float*)d_in[1];
    const float* rew  = (const float*)d_in[2];
    float* out = (float*)d_out;

    float* loss_out = out;
    float* svf = out + 1;
    int P  = (out_size - 1 - Bb * HW) / (Bb * 2);
    int ms = (P - 1) / (Tt - 1);
    float* pts = out + 1 + (size_t)Bb * HW;

    int*    count  = (int*)d_ws;
    double* vdot   = (double*)((char*)d_ws + 256);
    double* esum_p = (double*)((char*)d_ws + 768);
    double* edot_p = (double*)((char*)d_ws + 33536);

    fused_reduce_zero<<<Bb * 64, 256, 0, stream>>>(exps, rew, svf, esum_p, edot_p);
    scatter_batch<<<Bb, 256, 0, stream>>>(gt, rew, pts, svf, count, vdot, ms, P);
    loss_kernel<<<1, 64, 0, stream>>>(esum_p, edot_p, vdot, count, loss_out);
}

// Round 5
// 343.965 us; speedup vs baseline: 1.4475x; 1.0081x over previous
//
#include <hip/hip_runtime.h>

#define Bb 64
#define Tt 256
#define Hh 512
#define Ww 1024
#define HW (Hh * Ww)          // 524288
#define EPSF 1e-5f

typedef float vf4 __attribute__((ext_vector_type(4)));

// ws layout:
//   [0,256)        int    count[64]
//   [256,768)      double vdot[64]
//   [768,33536)    double esum_p[4096]   (64 blocks per batch)
//   [33536,66304)  double edot_p[4096]
// Everything is written before it is read -> no memset needed.

// ---------------------------------------------------------------------------
// Kernel A: batched float4 reads of exp_svf & reward (16 loads in flight per
// thread for MLP), nontemporal zero-fill of svf issued while loads drain,
// then accumulate. Per-block partials to distinct ws slots (no atomics).
// Block owns 8192 contiguous floats of one batch. Grid = 64*64 = 4096.
// ---------------------------------------------------------------------------
__global__ __launch_bounds__(256) void fused_reduce_zero(
        const float* __restrict__ exps, const float* __restrict__ rew,
        float* __restrict__ svf,
        double* __restrict__ esum_p, double* __restrict__ edot_p) {
    int b = blockIdx.x >> 6;
    int c = blockIdx.x & 63;
    size_t base = (size_t)b * HW + (size_t)c * 8192;

    const vf4* e4 = (const vf4*)(exps + base) + threadIdx.x;
    const vf4* r4 = (const vf4*)(rew + base) + threadIdx.x;

    // ---- issue ALL loads first: 16 outstanding 16B loads per thread ----
    vf4 ev[8], rv[8];
    #pragma unroll
    for (int k = 0; k < 8; ++k) ev[k] = e4[k * 256];
    #pragma unroll
    for (int k = 0; k < 8; ++k) rv[k] = r4[k * 256];

    // ---- zero-fill svf while loads are in flight ----
    // svf = out+1, so svf + base + 3 is 16B-aligned
    {
        vf4* z4 = (vf4*)(svf + base + 3);
        vf4 z = {0.f, 0.f, 0.f, 0.f};
        #pragma unroll
        for (int k = 0; k < 8; ++k) {
            int i = threadIdx.x + k * 256;
            if (i < 2047) __builtin_nontemporal_store(z, &z4[i]);
        }
        if (threadIdx.x < 3) svf[base + threadIdx.x] = 0.0f;
        if (threadIdx.x == 3) svf[base + 8191] = 0.0f;
    }

    // ---- accumulate ----
    float es = 0.0f, ed = 0.0f;
    #pragma unroll
    for (int k = 0; k < 8; ++k) {
        vf4 e = ev[k], r = rv[k];
        es += (e.x + e.y) + (e.z + e.w);
        ed += (e.x * r.x + e.y * r.y) + (e.z * r.z + e.w * r.w);
    }

    for (int off = 32; off; off >>= 1) {
        es += __shfl_down(es, off);
        ed += __shfl_down(ed, off);
    }
    __shared__ float s_es[4], s_ed[4];
    int lane = threadIdx.x & 63, wv = threadIdx.x >> 6;
    if (lane == 0) { s_es[wv] = es; s_ed[wv] = ed; }
    __syncthreads();
    if (threadIdx.x == 0) {
        float tes = (s_es[0] + s_es[1]) + (s_es[2] + s_es[3]);
        float ted = (s_ed[0] + s_ed[1]) + (s_ed[2] + s_ed[3]);
        esum_p[blockIdx.x] = (double)tes;
        edot_p[blockIdx.x] = (double)ted;
    }
}

// ---------------------------------------------------------------------------
// Point computation (bit-identical to what the reference produces at fp32)
// ---------------------------------------------------------------------------
__device__ __forceinline__ void comp_pt(const float* __restrict__ gt, int b,
                                        int idx, int ms, int segN,
                                        float& px, float& py) {
    if (idx < segN) {
        int seg = idx / ms;
        int k = idx - seg * ms;
        const float* g0 = gt + (size_t)(b * Tt + seg) * 9;
        float sx = g0[2] * 0.5f, sy = g0[5] * 0.5f;
        float ex = g0[11] * 0.5f, ey = g0[14] * 0.5f;
        float t = (ms > 1) ? (float)k / (float)(ms - 1) : 0.0f;
        px = __fadd_rn(sx, __fmul_rn(t, __fsub_rn(ex, sx)));
        py = __fadd_rn(sy, __fmul_rn(t, __fsub_rn(ey, sy)));
    } else {
        const float* g0 = gt + (size_t)(b * Tt + (Tt - 1)) * 9;
        px = g0[2] * 0.5f;
        py = g0[5] * 0.5f;
    }
}

__device__ __forceinline__ int pt_cell(float px, float py) {
    int xi = (int)fminf(fmaxf(px, 0.0f), (float)(Hh - 1));
    int yi = (int)fminf(fmaxf(py, 0.0f), (float)(Ww - 1));
    return xi * Ww + yi;
}

// ---------------------------------------------------------------------------
// Kernel B: one block per batch. Cells are MONOTONE along the point sequence
// (steps >= 0 -> both coords non-decreasing -> x*W+y non-decreasing), so
// dedup == adjacent-compare. No atomics anywhere.
// ---------------------------------------------------------------------------
__global__ __launch_bounds__(256) void scatter_batch(
        const float* __restrict__ gt, const float* __restrict__ rew,
        float* __restrict__ pts, float* __restrict__ svf,
        int* __restrict__ count_out, double* __restrict__ vdot_out,
        int ms, int P) {
    int b = blockIdx.x;
    int segN = (Tt - 1) * ms;

    int myCount = 0;
    float myV = 0.0f;
    for (int idx = threadIdx.x; idx < P; idx += 256) {
        float px, py;
        comp_pt(gt, b, idx, ms, segN, px, py);
        size_t pi = ((size_t)b * P + idx) * 2;
        pts[pi]     = px;
        pts[pi + 1] = py;
        int cell = pt_cell(px, py);
        bool claim;
        if (idx == 0) {
            claim = true;
        } else {
            float qx, qy;
            comp_pt(gt, b, idx - 1, ms, segN, qx, qy);
            claim = (pt_cell(qx, qy) != cell);
        }
        if (claim) {
            myCount++;
            myV += rew[(size_t)b * HW + cell];
        }
    }

    for (int off = 32; off; off >>= 1) {
        myCount += __shfl_down(myCount, off);
        myV     += __shfl_down(myV, off);
    }
    __shared__ int   sc[4];
    __shared__ float sv[4];
    __shared__ float s_recip;
    int lane = threadIdx.x & 63, wv = threadIdx.x >> 6;
    if (lane == 0) { sc[wv] = myCount; sv[wv] = myV; }
    __syncthreads();
    if (threadIdx.x == 0) {
        int tot  = (sc[0] + sc[1]) + (sc[2] + sc[3]);
        float tv = (sv[0] + sv[1]) + (sv[2] + sv[3]);
        count_out[b] = tot;
        vdot_out[b]  = (double)tv;
        s_recip = 1.0f / ((float)tot + EPSF);
    }
    __syncthreads();
    float recip = s_recip;

    // write recip at visited cells (duplicates write the identical value)
    for (int idx = threadIdx.x; idx < P; idx += 256) {
        size_t pi = ((size_t)b * P + idx) * 2;
        float px = pts[pi], py = pts[pi + 1];
        svf[(size_t)b * HW + pt_cell(px, py)] = recip;
    }
}

// ---------------------------------------------------------------------------
// Kernel C: loss
// ---------------------------------------------------------------------------
__global__ void loss_kernel(const double* __restrict__ esum_p,
                            const double* __restrict__ edot_p,
                            const double* __restrict__ vdot,
                            const int* __restrict__ count,
                            float* __restrict__ loss_out) {
    int b = threadIdx.x;  // 64 threads = 1 wave
    double es = 0.0, ed = 0.0;
    #pragma unroll 8
    for (int c = 0; c < 64; ++c) {
        es += esum_p[b * 64 + c];
        ed += edot_p[b * 64 + c];
    }
    double e = ed / (es + 1e-5);
    double v = vdot[b] / ((double)count[b] + 1e-5);
    double term = e - v;
    for (int off = 32; off; off >>= 1) term += __shfl_down(term, off);
    if (b == 0) loss_out[0] = (float)(term / (double)Bb);
}

extern "C" void kernel_launch(void* const* d_in, const int* in_sizes, int n_in,
                              void* d_out, int out_size, void* d_ws, size_t ws_size,
                              hipStream_t stream) {
    const float* gt   = (const float*)d_in[0];
    const float* exps = (const float*)d_in[1];
    const float* rew  = (const float*)d_in[2];
    float* out = (float*)d_out;

    float* loss_out = out;
    float* svf = out + 1;
    int P  = (out_size - 1 - Bb * HW) / (Bb * 2);
    int ms = (P - 1) / (Tt - 1);
    float* pts = out + 1 + (size_t)Bb * HW;

    int*    count  = (int*)d_ws;
    double* vdot   = (double*)((char*)d_ws + 256);
    double* esum_p = (double*)((char*)d_ws + 768);
    double* edot_p = (double*)((char*)d_ws + 33536);

    fused_reduce_zero<<<Bb * 64, 256, 0, stream>>>(exps, rew, svf, esum_p, edot_p);
    scatter_batch<<<Bb, 256, 0, stream>>>(gt, rew, pts, svf, count, vdot, ms, P);
    loss_kernel<<<1, 64, 0, stream>>>(esum_p, edot_p, vdot, count, loss_out);
}

// Round 6
// 335.046 us; speedup vs baseline: 1.4860x; 1.0266x over previous
//
#include <hip/hip_runtime.h>

#define Bb 64
#define Tt 256
#define Hh 512
#define Ww 1024
#define HW (Hh * Ww)          // 524288
#define EPSF 1e-5f

#define RB 2048               // reduce blocks (32 per batch)
#define SB Bb                 // scatter blocks (1 per batch)

typedef float vf4 __attribute__((ext_vector_type(4)));

// ws layout:
//   [0,256)         int    count[64]
//   [256,768)       double vdot[64]
//   [768,17152)     double esum_p[2048]
//   [17152,33536)   double edot_p[2048]
// Everything is written before it is read -> no ws memset needed.

// ---------------------------------------------------------------------------
// Point computation (bit-identical to the reference at fp32)
// ---------------------------------------------------------------------------
__device__ __forceinline__ void comp_pt(const float* __restrict__ gt, int b,
                                        int idx, int ms, int segN,
                                        float& px, float& py) {
    if (idx < segN) {
        int seg = idx / ms;
        int k = idx - seg * ms;
        const float* g0 = gt + (size_t)(b * Tt + seg) * 9;
        float sx = g0[2] * 0.5f, sy = g0[5] * 0.5f;
        float ex = g0[11] * 0.5f, ey = g0[14] * 0.5f;
        float t = (ms > 1) ? (float)k / (float)(ms - 1) : 0.0f;
        px = __fadd_rn(sx, __fmul_rn(t, __fsub_rn(ex, sx)));
        py = __fadd_rn(sy, __fmul_rn(t, __fsub_rn(ey, sy)));
    } else {
        const float* g0 = gt + (size_t)(b * Tt + (Tt - 1)) * 9;
        px = g0[2] * 0.5f;
        py = g0[5] * 0.5f;
    }
}

__device__ __forceinline__ int pt_cell(float px, float py) {
    int xi = (int)fminf(fmaxf(px, 0.0f), (float)(Hh - 1));
    int yi = (int)fminf(fmaxf(py, 0.0f), (float)(Ww - 1));
    return xi * Ww + yi;
}

// ---------------------------------------------------------------------------
// Combined kernel.
// Blocks [0, RB): PURE-READ reduce. Block owns 16384 contiguous floats of one
//   batch (32 blocks/batch); 2 iterations of 8 batched float4 loads per
//   stream. No stores except the per-block partial at the end.
// Blocks [RB, RB+SB): scatter. Cells are MONOTONE along the point sequence
//   (steps >= 0 -> coords non-decreasing -> x*W+y non-decreasing), so dedup
//   == adjacent-compare. Writes pts + svf[cell]=recip (svf was pre-zeroed by
//   the memset that precedes this kernel on the stream). No atomics anywhere.
// ---------------------------------------------------------------------------
__global__ __launch_bounds__(256) void combined_kernel(
        const float* __restrict__ exps, const float* __restrict__ rew,
        const float* __restrict__ gt,
        float* __restrict__ pts, float* __restrict__ svf,
        double* __restrict__ esum_p, double* __restrict__ edot_p,
        int* __restrict__ count_out, double* __restrict__ vdot_out,
        int ms, int P) {
    if (blockIdx.x < RB) {
        // ---------------- pure-read reduce ----------------
        int b = blockIdx.x >> 5;
        int c = blockIdx.x & 31;
        size_t base = (size_t)b * HW + (size_t)c * 16384;

        float es = 0.0f, ed = 0.0f;
        #pragma unroll
        for (int j = 0; j < 2; ++j) {
            const vf4* e4 = (const vf4*)(exps + base) + j * 2048 + threadIdx.x;
            const vf4* r4 = (const vf4*)(rew  + base) + j * 2048 + threadIdx.x;
            vf4 ev[8], rv[8];
            #pragma unroll
            for (int k = 0; k < 8; ++k) ev[k] = e4[k * 256];
            #pragma unroll
            for (int k = 0; k < 8; ++k) rv[k] = r4[k * 256];
            #pragma unroll
            for (int k = 0; k < 8; ++k) {
                vf4 e = ev[k], r = rv[k];
                es += (e.x + e.y) + (e.z + e.w);
                ed += (e.x * r.x + e.y * r.y) + (e.z * r.z + e.w * r.w);
            }
        }

        for (int off = 32; off; off >>= 1) {
            es += __shfl_down(es, off);
            ed += __shfl_down(ed, off);
        }
        __shared__ float s_es[4], s_ed[4];
        int lane = threadIdx.x & 63, wv = threadIdx.x >> 6;
        if (lane == 0) { s_es[wv] = es; s_ed[wv] = ed; }
        __syncthreads();
        if (threadIdx.x == 0) {
            float tes = (s_es[0] + s_es[1]) + (s_es[2] + s_es[3]);
            float ted = (s_ed[0] + s_ed[1]) + (s_ed[2] + s_ed[3]);
            esum_p[blockIdx.x] = (double)tes;
            edot_p[blockIdx.x] = (double)ted;
        }
    } else {
        // ---------------- scatter (1 block per batch) ----------------
        int b = blockIdx.x - RB;
        int segN = (Tt - 1) * ms;

        int myCount = 0;
        float myV = 0.0f;
        for (int idx = threadIdx.x; idx < P; idx += 256) {
            float px, py;
            comp_pt(gt, b, idx, ms, segN, px, py);
            size_t pi = ((size_t)b * P + idx) * 2;
            pts[pi]     = px;
            pts[pi + 1] = py;
            int cell = pt_cell(px, py);
            bool claim;
            if (idx == 0) {
                claim = true;
            } else {
                float qx, qy;
                comp_pt(gt, b, idx - 1, ms, segN, qx, qy);
                claim = (pt_cell(qx, qy) != cell);
            }
            if (claim) {
                myCount++;
                myV += rew[(size_t)b * HW + cell];
            }
        }

        for (int off = 32; off; off >>= 1) {
            myCount += __shfl_down(myCount, off);
            myV     += __shfl_down(myV, off);
        }
        __shared__ int   sc[4];
        __shared__ float sv[4];
        __shared__ float s_recip;
        int lane = threadIdx.x & 63, wv = threadIdx.x >> 6;
        if (lane == 0) { sc[wv] = myCount; sv[wv] = myV; }
        __syncthreads();
        if (threadIdx.x == 0) {
            int tot  = (sc[0] + sc[1]) + (sc[2] + sc[3]);
            float tv = (sv[0] + sv[1]) + (sv[2] + sv[3]);
            count_out[b] = tot;
            vdot_out[b]  = (double)tv;
            s_recip = 1.0f / ((float)tot + EPSF);
        }
        __syncthreads();
        float recip = s_recip;

        // write recip at visited cells (duplicates write the identical value)
        for (int idx = threadIdx.x; idx < P; idx += 256) {
            size_t pi = ((size_t)b * P + idx) * 2;
            float px = pts[pi], py = pts[pi + 1];
            svf[(size_t)b * HW + pt_cell(px, py)] = recip;
        }
    }
}

// ---------------------------------------------------------------------------
// Loss kernel
// ---------------------------------------------------------------------------
__global__ void loss_kernel(const double* __restrict__ esum_p,
                            const double* __restrict__ edot_p,
                            const double* __restrict__ vdot,
                            const int* __restrict__ count,
                            float* __restrict__ loss_out) {
    int b = threadIdx.x;  // 64 threads = 1 wave
    double es = 0.0, ed = 0.0;
    #pragma unroll 8
    for (int c = 0; c < 32; ++c) {
        es += esum_p[b * 32 + c];
        ed += edot_p[b * 32 + c];
    }
    double e = ed / (es + 1e-5);
    double v = vdot[b] / ((double)count[b] + 1e-5);
    double term = e - v;
    for (int off = 32; off; off >>= 1) term += __shfl_down(term, off);
    if (b == 0) loss_out[0] = (float)(term / (double)Bb);
}

extern "C" void kernel_launch(void* const* d_in, const int* in_sizes, int n_in,
                              void* d_out, int out_size, void* d_ws, size_t ws_size,
                              hipStream_t stream) {
    const float* gt   = (const float*)d_in[0];
    const float* exps = (const float*)d_in[1];
    const float* rew  = (const float*)d_in[2];
    float* out = (float*)d_out;

    float* loss_out = out;
    float* svf = out + 1;
    int P  = (out_size - 1 - Bb * HW) / (Bb * 2);
    int ms = (P - 1) / (Tt - 1);
    float* pts = out + 1 + (size_t)Bb * HW;

    int*    count  = (int*)d_ws;
    double* vdot   = (double*)((char*)d_ws + 256);
    double* esum_p = (double*)((char*)d_ws + 768);
    double* edot_p = (double*)((char*)d_ws + 17152);

    // write-only stream: driver memset lays down all svf zeros
    hipMemsetAsync(svf, 0, (size_t)Bb * HW * sizeof(float), stream);

    // read-only reduce + scatter in one launch
    combined_kernel<<<RB + SB, 256, 0, stream>>>(exps, rew, gt, pts, svf,
                                                 esum_p, edot_p, count, vdot,
                                                 ms, P);
    loss_kernel<<<1, 64, 0, stream>>>(esum_p, edot_p, vdot, count, loss_out);
}